// Round 4
// baseline (198.396 us; speedup 1.0000x reference)
//
#include <hip/hip_runtime.h>

#define NGRAPH 4096
#define NNODE  64
#define NDIM   128
#define NLAYER 3
#define PH 136   // sh pitch (bf16 elems); 272 B rows, 16B-aligned; bank-balanced for b128 (R3 data)
#define PZ 72    // szT pitch; 144 B rows, 16B-aligned

typedef __attribute__((ext_vector_type(8))) short short8;
typedef __attribute__((ext_vector_type(4))) float f32x4;
typedef __bf16 bf16x2 __attribute__((ext_vector_type(2)));

// W in bf16, native [l][k_out][d] layout: MFMA B-frag reads W rows directly, no transpose.
__device__ __align__(16) ushort g_wbf[NLAYER * NDIM * NDIM];

static __device__ inline ushort f2bf(float f) {  // RNE fp32 -> bf16 (fallback path)
  unsigned u = __float_as_uint(f);
  u += 0x7FFF + ((u >> 16) & 1);
  return (ushort)(u >> 16);
}

// packed fp32x2 -> bf16x2 in one HW instr on gfx950 (v_cvt_pk_bf16_f32)
static __device__ inline unsigned pkbf(float x, float y) {
#if __has_builtin(__builtin_amdgcn_cvt_pk_bf16_f32)
  bf16x2 v = __builtin_amdgcn_cvt_pk_bf16_f32(x, y);
  return __builtin_bit_cast(unsigned, v);
#else
  return (unsigned)f2bf(x) | ((unsigned)f2bf(y) << 16);
#endif
}

__global__ __launch_bounds__(256) void convert_w(const float* __restrict__ W) {
  int i = blockIdx.x * 256 + threadIdx.x;   // 192 blocks, exact
  g_wbf[i] = f2bf(W[i]);
}

__global__ __launch_bounds__(256, 4) void mpnn_mfma(
    const int* __restrict__ fps, const float* __restrict__ adj,
    const float* __restrict__ emb, const float* __restrict__ bias,
    float* __restrict__ out) {
  __shared__ __align__(16) ushort sh[NNODE * PH];   // h  bf16 [node][d]   17408 B
  __shared__ __align__(16) ushort szT[NDIM * PZ];   // zT bf16 [k|d][node] 18432 B

  const int g    = blockIdx.x;
  const int t    = threadIdx.x;
  const int w    = t >> 6;        // wave 0..3
  const int lane = t & 63;
  const int r    = lane & 15;     // MFMA row/col index
  const int q    = lane >> 4;     // quad 0..3
  const int n0   = w << 5;        // wave's 32-wide k_out slab (m1) == d slab (m2)

  // ---- gather h0 = bf16(emb[fps]) ----
  const int* fg = fps + g * NNODE;
#pragma unroll
  for (int it = 0; it < 8; ++it) {
    int idx = it * 256 + t;               // 2048 float4s
    int n = idx >> 5;
    int c = (idx & 31) << 2;
    float4 v = *(const float4*)(emb + fg[n] * NDIM + c);
    uint2 u = {pkbf(v.x, v.y), pkbf(v.z, v.w)};
    *(uint2*)(sh + n * PH + c) = u;
  }

  // ---- adjacency fragments -> registers (hi/lo split of A' = I + A) ----
  const float* adjg = adj + (size_t)g * NNODE * NNODE;
  short8 fadj[4][4];
  union S8 { short8 s8; unsigned d[4]; };
#pragma unroll
  for (int nt = 0; nt < 4; ++nt) {
    int row = nt * 16 + r;                // output node (B-frag column)
    const float* rp = adjg + row * NNODE;
#pragma unroll
    for (int kh = 0; kh < 2; ++kh) {
      int cb = kh * 32 + 8 * q;           // k (source node) base
      float4 v0 = *(const float4*)(rp + cb);
      float4 v1 = *(const float4*)(rp + cb + 4);
      float vv[8] = {v0.x, v0.y, v0.z, v0.w, v1.x, v1.y, v1.z, v1.w};
      if ((nt >> 1) == kh) {              // diagonal can only hit these tiles
#pragma unroll
        for (int j = 0; j < 8; ++j)
          if (row == cb + j) vv[j] += 1.0f;
      }
      S8 hi, lo;
#pragma unroll
      for (int jp = 0; jp < 4; ++jp) {
        unsigned hp = pkbf(vv[2 * jp], vv[2 * jp + 1]);
        hi.d[jp] = hp;
        float h0 = __uint_as_float(hp << 16);          // bf2f of low half
        float h1 = __uint_as_float(hp & 0xFFFF0000u);  // bf2f of high half
        lo.d[jp] = pkbf(vv[2 * jp] - h0, vv[2 * jp + 1] - h1);
      }
      fadj[nt][kh]     = hi.s8;
      fadj[nt][2 + kh] = lo.s8;
    }
  }
  __syncthreads();

  for (int l = 0; l < NLAYER; ++l) {
    const ushort* Wl = g_wbf + l * NDIM * NDIM;
    const float*  bl = bias + l * NDIM;

    // ---- m1: z[node][n0-slab] = relu(h * W^T + b)  (A = h rows, B = W rows) ----
    f32x4 acc[4][2];
#pragma unroll
    for (int nt = 0; nt < 2; ++nt) {
      float bv = bl[n0 + nt * 16 + r];
#pragma unroll
      for (int mt = 0; mt < 4; ++mt) acc[mt][nt] = (f32x4){bv, bv, bv, bv};
    }
#pragma unroll
    for (int k0 = 0; k0 < NDIM; k0 += 32) {
      short8 bw0 = *(const short8*)(Wl + (n0 + r) * NDIM + k0 + 8 * q);
      short8 bw1 = *(const short8*)(Wl + (n0 + 16 + r) * NDIM + k0 + 8 * q);
#pragma unroll
      for (int mt = 0; mt < 4; ++mt) {
        short8 ah = *(const short8*)(sh + (mt * 16 + r) * PH + k0 + 8 * q);
        acc[mt][0] = __builtin_amdgcn_mfma_f32_16x16x32_bf16(ah, bw0, acc[mt][0], 0, 0, 0);
        acc[mt][1] = __builtin_amdgcn_mfma_f32_16x16x32_bf16(ah, bw1, acc[mt][1], 0, 0, 0);
      }
    }
    // relu -> bf16 -> szT[k_out][node]  (C-frag: 4 consecutive nodes per lane)
#pragma unroll
    for (int mt = 0; mt < 4; ++mt)
#pragma unroll
      for (int nt = 0; nt < 2; ++nt) {
        f32x4 a = acc[mt][nt];
        uint2 u = {pkbf(fmaxf(a[0], 0.f), fmaxf(a[1], 0.f)),
                   pkbf(fmaxf(a[2], 0.f), fmaxf(a[3], 0.f))};
        *(uint2*)(szT + (n0 + nt * 16 + r) * PZ + mt * 16 + 4 * q) = u;
      }

    // ---- m2: houtT[d in n0-slab][node] = zT * (I+A)^T  (A = own szT rows, B = reg adj) ----
    f32x4 acc2[2][4];
#pragma unroll
    for (int mt = 0; mt < 2; ++mt)
#pragma unroll
      for (int nt = 0; nt < 4; ++nt) acc2[mt][nt] = (f32x4){0.f, 0.f, 0.f, 0.f};
#pragma unroll
    for (int kh = 0; kh < 2; ++kh) {
#pragma unroll
      for (int mt = 0; mt < 2; ++mt) {
        short8 az = *(const short8*)(szT + (n0 + mt * 16 + r) * PZ + kh * 32 + 8 * q);
#pragma unroll
        for (int nt = 0; nt < 4; ++nt) {
          acc2[mt][nt] = __builtin_amdgcn_mfma_f32_16x16x32_bf16(az, fadj[nt][kh], acc2[mt][nt], 0, 0, 0);
          acc2[mt][nt] = __builtin_amdgcn_mfma_f32_16x16x32_bf16(az, fadj[nt][2 + kh], acc2[mt][nt], 0, 0, 0);
        }
      }
    }

    if (l < NLAYER - 1) {
      __syncthreads();   // all waves done reading sh (m1 A-frags)
#pragma unroll
      for (int mt = 0; mt < 2; ++mt)
#pragma unroll
        for (int nt = 0; nt < 4; ++nt) {
          f32x4 a = acc2[mt][nt];
          uint2 u = {pkbf(a[0], a[1]), pkbf(a[2], a[3])};
          *(uint2*)(sh + (nt * 16 + r) * PH + n0 + mt * 16 + 4 * q) = u;
        }
      __syncthreads();   // sh ready for next layer
    } else {
      // ---- sum-pool from C-frags: out[g][d] = sum_node houtT[d][node] ----
#pragma unroll
      for (int mt = 0; mt < 2; ++mt) {
        f32x4 s;
#pragma unroll
        for (int i = 0; i < 4; ++i)
          s[i] = acc2[mt][0][i] + acc2[mt][1][i] + acc2[mt][2][i] + acc2[mt][3][i];
#pragma unroll
        for (int m = 1; m <= 8; m <<= 1) {
          s[0] += __shfl_xor(s[0], m);
          s[1] += __shfl_xor(s[1], m);
          s[2] += __shfl_xor(s[2], m);
          s[3] += __shfl_xor(s[3], m);
        }
        if (r == 0) {
          float4 o = {s[0], s[1], s[2], s[3]};
          *(float4*)(out + (size_t)g * NDIM + n0 + mt * 16 + 4 * q) = o;
        }
      }
    }
  }
}

extern "C" void kernel_launch(void* const* d_in, const int* in_sizes, int n_in,
                              void* d_out, int out_size, void* d_ws, size_t ws_size,
                              hipStream_t stream) {
  const int*   fps  = (const int*)d_in[0];
  const float* adj  = (const float*)d_in[1];
  const float* emb  = (const float*)d_in[2];
  const float* W    = (const float*)d_in[3];
  const float* bias = (const float*)d_in[4];
  float* out = (float*)d_out;

  hipLaunchKernelGGL(convert_w, dim3(192), dim3(256), 0, stream, W);
  hipLaunchKernelGGL(mpnn_mfma, dim3(NGRAPH), dim3(256), 0, stream,
                     fps, adj, emb, bias, out);
}

// Round 5
// 176.828 us; speedup vs baseline: 1.1220x; 1.1220x over previous
//
#include <hip/hip_runtime.h>

#define NGRAPH 4096
#define NNODE  64
#define NDIM   128
#define NLAYER 3
#define PH 136   // sh pitch (bf16): 68 dwords === 4 mod 32 -> 2-way-max (free) b128 row reads
#define PZ 72    // szT pitch: 36 dwords === 4 mod 32

typedef __attribute__((ext_vector_type(8))) short short8;
typedef __attribute__((ext_vector_type(4))) float f32x4;
typedef __bf16 bf16x2 __attribute__((ext_vector_type(2)));

// W in bf16, native [l][k_out][d] layout: MFMA B-frag reads W rows directly, no transpose.
__device__ __align__(16) ushort g_wbf[NLAYER * NDIM * NDIM];

static __device__ inline ushort f2bf(float f) {  // RNE fp32 -> bf16 (fallback path)
  unsigned u = __float_as_uint(f);
  u += 0x7FFF + ((u >> 16) & 1);
  return (ushort)(u >> 16);
}

// packed fp32x2 -> bf16x2 in one HW instr on gfx950 (v_cvt_pk_bf16_f32)
static __device__ inline unsigned pkbf(float x, float y) {
#if __has_builtin(__builtin_amdgcn_cvt_pk_bf16_f32)
  bf16x2 v = __builtin_amdgcn_cvt_pk_bf16_f32(x, y);
  return __builtin_bit_cast(unsigned, v);
#else
  return (unsigned)f2bf(x) | ((unsigned)f2bf(y) << 16);
#endif
}

__global__ __launch_bounds__(256) void convert_w(const float* __restrict__ W) {
  int i = blockIdx.x * 256 + threadIdx.x;   // 192 blocks, exact
  g_wbf[i] = f2bf(W[i]);
}

__global__ __launch_bounds__(256, 4) void mpnn_mfma(
    const int* __restrict__ fps, const float* __restrict__ adj,
    const float* __restrict__ emb, const float* __restrict__ bias,
    float* __restrict__ out) {
  __shared__ __align__(16) ushort sh[NNODE * PH];   // h  bf16 [node][d]   17408 B
  __shared__ __align__(16) ushort szT[NDIM * PZ];   // zT bf16 [k|d][node] 18432 B

  const int g    = blockIdx.x;
  const int t    = threadIdx.x;
  const int w    = t >> 6;        // wave 0..3
  const int lane = t & 63;
  const int r    = lane & 15;     // MFMA row/col index
  const int q    = lane >> 4;     // quad 0..3
  const int n0   = w << 5;        // wave's 32-wide k_out slab (m1) == d slab (m2)

  // ---- gather h0 = bf16(emb[fps]) ----
  const int* fg = fps + g * NNODE;
#pragma unroll
  for (int it = 0; it < 8; ++it) {
    int idx = it * 256 + t;               // 2048 float4s
    int n = idx >> 5;
    int c = (idx & 31) << 2;
    float4 v = *(const float4*)(emb + fg[n] * NDIM + c);
    uint2 u = {pkbf(v.x, v.y), pkbf(v.z, v.w)};
    *(uint2*)(sh + n * PH + c) = u;
  }

  // ---- adjacency fragments -> registers: single bf16 of A' = I + A (32 VGPRs) ----
  const float* adjg = adj + (size_t)g * NNODE * NNODE;
  short8 fadj[4][2];
  union S8 { short8 s8; unsigned d[4]; };
#pragma unroll
  for (int nt = 0; nt < 4; ++nt) {
    int row = nt * 16 + r;                // output node (B-frag column)
    const float* rp = adjg + row * NNODE;
#pragma unroll
    for (int kh = 0; kh < 2; ++kh) {
      int cb = kh * 32 + 8 * q;           // k (source node) base
      float4 v0 = *(const float4*)(rp + cb);
      float4 v1 = *(const float4*)(rp + cb + 4);
      float vv[8] = {v0.x, v0.y, v0.z, v0.w, v1.x, v1.y, v1.z, v1.w};
      if ((nt >> 1) == kh) {              // diagonal can only hit these tiles
#pragma unroll
        for (int j = 0; j < 8; ++j)
          if (row == cb + j) vv[j] += 1.0f;
      }
      S8 hi;
#pragma unroll
      for (int jp = 0; jp < 4; ++jp) hi.d[jp] = pkbf(vv[2 * jp], vv[2 * jp + 1]);
      fadj[nt][kh] = hi.s8;
    }
  }
  __syncthreads();

  for (int l = 0; l < NLAYER; ++l) {
    const ushort* Wl = g_wbf + l * NDIM * NDIM;
    const float*  bl = bias + l * NDIM;

    // ---- m1: z[node][n0-slab] = relu(h * W^T + b)  (A = h rows, B = W rows) ----
    f32x4 acc[4][2];
#pragma unroll
    for (int nt = 0; nt < 2; ++nt) {
      float bv = bl[n0 + nt * 16 + r];
#pragma unroll
      for (int mt = 0; mt < 4; ++mt) acc[mt][nt] = (f32x4){bv, bv, bv, bv};
    }
#pragma unroll
    for (int k0 = 0; k0 < NDIM; k0 += 32) {
      short8 bw0 = *(const short8*)(Wl + (n0 + r) * NDIM + k0 + 8 * q);
      short8 bw1 = *(const short8*)(Wl + (n0 + 16 + r) * NDIM + k0 + 8 * q);
#pragma unroll
      for (int mt = 0; mt < 4; ++mt) {
        short8 ah = *(const short8*)(sh + (mt * 16 + r) * PH + k0 + 8 * q);
        acc[mt][0] = __builtin_amdgcn_mfma_f32_16x16x32_bf16(ah, bw0, acc[mt][0], 0, 0, 0);
        acc[mt][1] = __builtin_amdgcn_mfma_f32_16x16x32_bf16(ah, bw1, acc[mt][1], 0, 0, 0);
      }
    }
    // relu -> bf16 -> szT[k_out][node]  (C-frag: 4 consecutive nodes per lane)
#pragma unroll
    for (int mt = 0; mt < 4; ++mt)
#pragma unroll
      for (int nt = 0; nt < 2; ++nt) {
        f32x4 a = acc[mt][nt];
        uint2 u = {pkbf(fmaxf(a[0], 0.f), fmaxf(a[1], 0.f)),
                   pkbf(fmaxf(a[2], 0.f), fmaxf(a[3], 0.f))};
        *(uint2*)(szT + (n0 + nt * 16 + r) * PZ + mt * 16 + 4 * q) = u;
      }

    // ---- m2: houtT[d in n0-slab][node] = zT * (I+A)^T  (A = own szT rows, B = reg adj) ----
    f32x4 acc2[2][4];
#pragma unroll
    for (int mt = 0; mt < 2; ++mt)
#pragma unroll
      for (int nt = 0; nt < 4; ++nt) acc2[mt][nt] = (f32x4){0.f, 0.f, 0.f, 0.f};
#pragma unroll
    for (int kh = 0; kh < 2; ++kh) {
#pragma unroll
      for (int mt = 0; mt < 2; ++mt) {
        short8 az = *(const short8*)(szT + (n0 + mt * 16 + r) * PZ + kh * 32 + 8 * q);
#pragma unroll
        for (int nt = 0; nt < 4; ++nt)
          acc2[mt][nt] = __builtin_amdgcn_mfma_f32_16x16x32_bf16(az, fadj[nt][kh], acc2[mt][nt], 0, 0, 0);
      }
    }

    if (l < NLAYER - 1) {
      __syncthreads();   // all waves done reading sh (m1 A-frags)
#pragma unroll
      for (int mt = 0; mt < 2; ++mt)
#pragma unroll
        for (int nt = 0; nt < 4; ++nt) {
          f32x4 a = acc2[mt][nt];
          uint2 u = {pkbf(a[0], a[1]), pkbf(a[2], a[3])};
          *(uint2*)(sh + (nt * 16 + r) * PH + n0 + mt * 16 + 4 * q) = u;
        }
      __syncthreads();   // sh ready for next layer
    } else {
      // ---- sum-pool from C-frags: out[g][d] = sum_node houtT[d][node] ----
#pragma unroll
      for (int mt = 0; mt < 2; ++mt) {
        f32x4 s;
#pragma unroll
        for (int i = 0; i < 4; ++i)
          s[i] = acc2[mt][0][i] + acc2[mt][1][i] + acc2[mt][2][i] + acc2[mt][3][i];
#pragma unroll
        for (int m = 1; m <= 8; m <<= 1) {
          s[0] += __shfl_xor(s[0], m);
          s[1] += __shfl_xor(s[1], m);
          s[2] += __shfl_xor(s[2], m);
          s[3] += __shfl_xor(s[3], m);
        }
        if (r == 0) {
          float4 o = {s[0], s[1], s[2], s[3]};
          *(float4*)(out + (size_t)g * NDIM + n0 + mt * 16 + 4 * q) = o;
        }
      }
    }
  }
}

extern "C" void kernel_launch(void* const* d_in, const int* in_sizes, int n_in,
                              void* d_out, int out_size, void* d_ws, size_t ws_size,
                              hipStream_t stream) {
  const int*   fps  = (const int*)d_in[0];
  const float* adj  = (const float*)d_in[1];
  const float* emb  = (const float*)d_in[2];
  const float* W    = (const float*)d_in[3];
  const float* bias = (const float*)d_in[4];
  float* out = (float*)d_out;

  hipLaunchKernelGGL(convert_w, dim3(192), dim3(256), 0, stream, W);
  hipLaunchKernelGGL(mpnn_mfma, dim3(NGRAPH), dim3(256), 0, stream,
                     fps, adj, emb, bias, out);
}